// Round 8
// baseline (919.411 us; speedup 1.0000x reference)
//
#include <hip/hip_runtime.h>
#include <hip/hip_bf16.h>
#include <cstdint>
#include <cstddef>

#define BN_EPS 1e-3f
#define CHUNK_SHIFT 13   // col-chunk = 8192 cols -> 2.1 MB of hb, fits 4MB/XCD L2

typedef __attribute__((ext_vector_type(8))) short bf16x8;
typedef __attribute__((ext_vector_type(4))) float f32x4;

__device__ __forceinline__ float blo(unsigned u) {
  union { unsigned i; float f; } v; v.i = u << 16; return v.f;
}
__device__ __forceinline__ float bhi(unsigned u) {
  union { unsigned i; float f; } v; v.i = u & 0xffff0000u; return v.f;
}
__device__ __forceinline__ unsigned pk2(float a, float b) {
  __hip_bfloat162 t = __float22bfloat162_rn(make_float2(a, b));
  return *reinterpret_cast<unsigned*>(&t);
}
__device__ __forceinline__ void acc_pk(float* acc, uint4 u) {
  acc[0] += blo(u.x); acc[1] += bhi(u.x);
  acc[2] += blo(u.y); acc[3] += bhi(u.y);
  acc[4] += blo(u.z); acc[5] += bhi(u.z);
  acc[6] += blo(u.w); acc[7] += bhi(u.w);
}

// ---------------------------------------------------------------------------
// Embedding MFMA tile body (shared by fill_emb). Reads x fp32, cvt in-reg.
// hb = bf16(relu(x @ Wet^T + bias)). 64x128 tile, 4 waves 2x2.
// ---------------------------------------------------------------------------
__device__ __forceinline__ void emb_tile(
    const float* __restrict__ x,
    const __hip_bfloat16* __restrict__ Bt,   // [128][96]
    const float* __restrict__ bias,
    __hip_bfloat16* __restrict__ hb, int N, int Fn, int m0, int tid)
{
  constexpr int KP = 96;
  const int w    = tid >> 6, lane = tid & 63;
  const int wr   = w >> 1,   wc   = w & 1;
  const int lr   = lane & 15;
  const int kg   = lane >> 4;

  f32x4 acc[2][4] = {};
  const int rowA0 = m0 + wr * 32 + lr;

  #pragma unroll
  for (int ks = 0; ks < KP / 32; ks++) {
    const int k0 = ks * 32 + kg * 8;
    bf16x8 a[2], b[4];
    #pragma unroll
    for (int m = 0; m < 2; m++) {
      int r = rowA0 + m * 16;
      r = (r < N) ? r : 0;
      const float* px = &x[(size_t)r * Fn + k0];
      float4 v0 = make_float4(0.f, 0.f, 0.f, 0.f);
      float4 v1 = make_float4(0.f, 0.f, 0.f, 0.f);
      if (k0 + 8 <= Fn) {
        v0 = *reinterpret_cast<const float4*>(px);
        v1 = *reinterpret_cast<const float4*>(px + 4);
      } else if (k0 + 4 <= Fn) {
        v0 = *reinterpret_cast<const float4*>(px);
        if (k0 + 5 <= Fn) v1.x = px[4];
        if (k0 + 6 <= Fn) v1.y = px[5];
        if (k0 + 7 <= Fn) v1.z = px[6];
      } else if (k0 < Fn) {
        if (k0 + 1 <= Fn) v0.x = px[0];
        if (k0 + 2 <= Fn) v0.y = px[1];
        if (k0 + 3 <= Fn) v0.z = px[2];
      }
      uint4 pu;
      pu.x = pk2(v0.x, v0.y); pu.y = pk2(v0.z, v0.w);
      pu.z = pk2(v1.x, v1.y); pu.w = pk2(v1.z, v1.w);
      a[m] = *reinterpret_cast<bf16x8*>(&pu);
    }
    #pragma unroll
    for (int n = 0; n < 4; n++) {
      int c = wc * 64 + n * 16 + lr;
      b[n] = *reinterpret_cast<const bf16x8*>(&Bt[(size_t)c * KP + k0]);
    }
    #pragma unroll
    for (int m = 0; m < 2; m++)
      #pragma unroll
      for (int n = 0; n < 4; n++)
        acc[m][n] = __builtin_amdgcn_mfma_f32_16x16x32_bf16(a[m], b[n], acc[m][n], 0, 0, 0);
  }

  #pragma unroll
  for (int n = 0; n < 4; n++) {
    const int c = wc * 64 + n * 16 + lr;
    const float bb = bias[c];
    #pragma unroll
    for (int m = 0; m < 2; m++) {
      #pragma unroll
      for (int j = 0; j < 4; j++) {
        int grow = m0 + wr * 32 + m * 16 + kg * 4 + j;
        if (grow < N) {
          float v = fmaxf(acc[m][n][j] + bb, 0.f);
          hb[(size_t)grow * 128 + c] = __float2bfloat16(v);
        }
      }
    }
  }
}

// ---------------------------------------------------------------------------
// Fused conv layer, bf16 residual chain, COLUMN-CHUNKED gather:
// CSR is keyed by row*NC + (col>>CHUNK_SHIFT); the gather loops chunk-major
// so all blocks read hb cols from one ~2MB window at a time -> L2-resident.
// Register accumulators per group-row persist across chunks.
//   hbo = bf16( hbi + relu( (gather(hbi) ++ T) @ Wct / deg * bn_scale + ofs ) )
// ---------------------------------------------------------------------------
template<bool GATHER_T>
__global__ __launch_bounds__(256) void conv_fused(
    const __hip_bfloat16* __restrict__ hbi,
    const int* __restrict__ row_ptr,          // [N*NC+1]
    const int* __restrict__ csr_col,
    const int* __restrict__ csr_eid,
    const float* __restrict__ eattr,
    __hip_bfloat16* __restrict__ Tb,          // [N][64] out (l0) / in (l1,l2)
    const __hip_bfloat16* __restrict__ Wct,   // [128][192]
    const float* __restrict__ bc,
    const float* __restrict__ gamma,
    const float* __restrict__ beta,
    __hip_bfloat16* __restrict__ hbo, int N, int NC)
{
  constexpr int K   = 192;
  constexpr int LDK = 200;
  __shared__ __hip_bfloat16 As[64 * LDK];   // 25.6 KB
  __shared__ float sinv[64];

  const int tid = threadIdx.x;
  const int m0  = blockIdx.x * 64;

  // ---- gather phase: 16 groups x 16 lanes; group g owns rows {g,g+16,g+32,g+48}
  {
    const int g   = tid >> 4;
    const int gl  = tid & 15;
    const int gb  = (tid & 63) & ~15;    // group base lane within wave (for shfl)

    float acc[4][8] = {};
    float tacc[4][4] = {};

    for (int ch = 0; ch < NC; ch++) {
      #pragma unroll
      for (int rr = 0; rr < 4; rr++) {
        const int gr = m0 + g + rr * 16;
        if (gr >= N) continue;
        const int key = gr * NC + ch;
        const int s   = row_ptr[key];
        const int len = row_ptr[key + 1] - s;
        for (int b = 0; b < len; b += 16) {
          const int m  = min(16, len - b);
          const int cv = (gl < m) ? csr_col[s + b + gl] : 0;
          int ev = 0;
          if (GATHER_T) ev = (gl < m) ? csr_eid[s + b + gl] : 0;
          int j = 0;
          for (; j + 8 <= m; j += 8) {
            uint4 u[8];
            #pragma unroll
            for (int t = 0; t < 8; t++) {
              int c = __shfl(cv, gb + j + t);
              u[t] = *reinterpret_cast<const uint4*>(&hbi[(size_t)c * 128 + gl * 8]);
            }
            #pragma unroll
            for (int t = 0; t < 8; t++) acc_pk(acc[rr], u[t]);
          }
          for (; j + 4 <= m; j += 4) {
            uint4 u[4];
            #pragma unroll
            for (int t = 0; t < 4; t++) {
              int c = __shfl(cv, gb + j + t);
              u[t] = *reinterpret_cast<const uint4*>(&hbi[(size_t)c * 128 + gl * 8]);
            }
            #pragma unroll
            for (int t = 0; t < 4; t++) acc_pk(acc[rr], u[t]);
          }
          for (; j < m; ++j) {
            int c = __shfl(cv, gb + j);
            uint4 u = *reinterpret_cast<const uint4*>(&hbi[(size_t)c * 128 + gl * 8]);
            acc_pk(acc[rr], u);
          }
          if (GATHER_T) {
            int j2 = 0;
            for (; j2 + 4 <= m; j2 += 4) {
              float4 t0, t1, t2, t3;
              {
                int e0 = __shfl(ev, gb + j2 + 0), e1 = __shfl(ev, gb + j2 + 1);
                int e2 = __shfl(ev, gb + j2 + 2), e3 = __shfl(ev, gb + j2 + 3);
                t0 = *reinterpret_cast<const float4*>(&eattr[(size_t)e0 * 64 + gl * 4]);
                t1 = *reinterpret_cast<const float4*>(&eattr[(size_t)e1 * 64 + gl * 4]);
                t2 = *reinterpret_cast<const float4*>(&eattr[(size_t)e2 * 64 + gl * 4]);
                t3 = *reinterpret_cast<const float4*>(&eattr[(size_t)e3 * 64 + gl * 4]);
              }
              tacc[rr][0] += (t0.x + t1.x) + (t2.x + t3.x);
              tacc[rr][1] += (t0.y + t1.y) + (t2.y + t3.y);
              tacc[rr][2] += (t0.z + t1.z) + (t2.z + t3.z);
              tacc[rr][3] += (t0.w + t1.w) + (t2.w + t3.w);
            }
            for (; j2 < m; ++j2) {
              int e0 = __shfl(ev, gb + j2);
              float4 t0 = *reinterpret_cast<const float4*>(&eattr[(size_t)e0 * 64 + gl * 4]);
              tacc[rr][0] += t0.x; tacc[rr][1] += t0.y;
              tacc[rr][2] += t0.z; tacc[rr][3] += t0.w;
            }
          }
        }
      }
    }

    // ---- write-out to LDS (+ Tb / sinv)
    #pragma unroll
    for (int rr = 0; rr < 4; rr++) {
      const int r  = g + rr * 16;
      const int gr = m0 + r;
      if (gr < N) {
        uint4 o;
        o.x = pk2(acc[rr][0], acc[rr][1]); o.y = pk2(acc[rr][2], acc[rr][3]);
        o.z = pk2(acc[rr][4], acc[rr][5]); o.w = pk2(acc[rr][6], acc[rr][7]);
        *reinterpret_cast<uint4*>(&As[r * LDK + gl * 8]) = o;
        if (GATHER_T) {
          uint2 tw;
          tw.x = pk2(tacc[rr][0], tacc[rr][1]); tw.y = pk2(tacc[rr][2], tacc[rr][3]);
          *reinterpret_cast<uint2*>(&As[r * LDK + 128 + gl * 4]) = tw;
          *reinterpret_cast<uint2*>(&Tb[(size_t)gr * 64 + gl * 4]) = tw;
        }
        if (gl == 0) {
          int lt = row_ptr[(gr + 1) * NC] - row_ptr[gr * NC];
          sinv[r] = 1.f / fmaxf(1.f, (float)lt);
        }
      } else if (gl == 0) {
        sinv[r] = 1.f;
      }
    }
  }
  if (!GATHER_T) {
    // ---- T-tile copy: 64 rows x 64 cols bf16
    #pragma unroll
    for (int it = 0; it < 2; it++) {
      int idx = tid + it * 256;
      int r   = idx >> 3;
      int ko  = (idx & 7) * 8;
      int gr  = m0 + r;
      uint4 v = make_uint4(0, 0, 0, 0);
      if (gr < N) v = *reinterpret_cast<const uint4*>(&Tb[(size_t)gr * 64 + ko]);
      *reinterpret_cast<uint4*>(&As[r * LDK + 128 + ko]) = v;
    }
  }
  __syncthreads();

  // ---- MFMA phase
  const int w    = tid >> 6, lane = tid & 63;
  const int wr   = w >> 1,   wc   = w & 1;
  const int lr   = lane & 15;
  const int kg   = lane >> 4;

  f32x4 acc[2][4] = {};
  #pragma unroll
  for (int ks = 0; ks < K / 32; ks++) {
    const int k0 = ks * 32 + kg * 8;
    bf16x8 a[2], b[4];
    #pragma unroll
    for (int m = 0; m < 2; m++) {
      int r = wr * 32 + lr + m * 16;
      a[m] = *reinterpret_cast<const bf16x8*>(&As[r * LDK + k0]);
    }
    #pragma unroll
    for (int n = 0; n < 4; n++) {
      int c = wc * 64 + n * 16 + lr;
      b[n] = *reinterpret_cast<const bf16x8*>(&Wct[(size_t)c * K + k0]);
    }
    #pragma unroll
    for (int m = 0; m < 2; m++)
      #pragma unroll
      for (int n = 0; n < 4; n++)
        acc[m][n] = __builtin_amdgcn_mfma_f32_16x16x32_bf16(a[m], b[n], acc[m][n], 0, 0, 0);
  }

  const float rs = rsqrtf(1.f + BN_EPS);
  #pragma unroll
  for (int n = 0; n < 4; n++) {
    const int c   = wc * 64 + n * 16 + lr;
    const float sc  = gamma[c] * rs;
    const float ofs = bc[c] * sc + beta[c];
    #pragma unroll
    for (int m = 0; m < 2; m++) {
      #pragma unroll
      for (int j = 0; j < 4; j++) {
        int lrow = wr * 32 + m * 16 + kg * 4 + j;
        int grow = m0 + lrow;
        if (grow < N) {
          float v    = acc[m][n][j] * sc * sinv[lrow] + ofs;
          float hold = __bfloat162float(hbi[(size_t)grow * 128 + c]);
          float hn   = hold + fmaxf(v, 0.f);
          hbo[(size_t)grow * 128 + c] = __float2bfloat16(hn);
        }
      }
    }
  }
}

// ---------------------------------------------------------------------------
// K1: blocks [0,wb) convert weights; blocks [wb,..) chunked histogram
// (cnt pre-zeroed by memsetAsync). key = row*NC + (col>>CHUNK_SHIFT).
// ---------------------------------------------------------------------------
__global__ void prep_hist(
    const float* __restrict__ W_emb, __hip_bfloat16* __restrict__ Wet,
    const float* __restrict__ Wc, __hip_bfloat16* __restrict__ Wct,
    const int* __restrict__ rows, const int* __restrict__ cols,
    int* __restrict__ cnt,
    int E, int wb, int Fn, int Kp, int H, int L, int Kc, int NC)
{
  if ((int)blockIdx.x < wb) {
    int i = blockIdx.x * 256 + threadIdx.x;
    if (i < H * Kp) {
      int c = i / Kp, k = i - c * Kp;
      Wet[i] = __float2bfloat16(k < Fn ? W_emb[(size_t)k * H + c] : 0.f);
    } else if (i < H * Kp + L * H * Kc) {
      int j = i - H * Kp;
      int l   = j / (H * Kc);
      int rem = j - l * (H * Kc);
      int c   = rem / Kc;
      int k   = rem - c * Kc;
      Wct[j] = __float2bfloat16(Wc[(size_t)l * Kc * H + (size_t)k * H + c]);
    }
  } else {
    int e = (blockIdx.x - wb) * 256 + threadIdx.x;
    if (e < E) {
      int key = rows[e] * NC + (cols[e] >> CHUNK_SHIFT);
      atomicAdd(&cnt[key], 1);
    }
  }
}

__global__ __launch_bounds__(1024) void scan_kernel(const int* __restrict__ cnt,
                                                    int* __restrict__ row_ptr, int M) {
  __shared__ int wsum[16];
  __shared__ int woff[16];
  __shared__ int carry;
  const int tid  = threadIdx.x;
  const int lane = tid & 63, wid = tid >> 6;
  if (tid == 0) { carry = 0; row_ptr[0] = 0; }
  __syncthreads();
  for (int base = 0; base < M; base += 8192) {
    int c = carry;
    int v[8]; int s = 0;
    #pragma unroll
    for (int i = 0; i < 8; i++) {
      int idx = base + tid * 8 + i;
      v[i] = (idx < M) ? cnt[idx] : 0;
      s += v[i];
    }
    int sc = s;
    #pragma unroll
    for (int o = 1; o < 64; o <<= 1) {
      int u = __shfl_up(sc, o);
      if (lane >= o) sc += u;
    }
    if (lane == 63) wsum[wid] = sc;
    __syncthreads();
    if (tid == 0) {
      int run = 0;
      for (int i = 0; i < 16; i++) { int t = wsum[i]; woff[i] = run; run += t; }
      carry = c + run;
    }
    __syncthreads();
    int run = c + woff[wid] + (sc - s);
    #pragma unroll
    for (int i = 0; i < 8; i++) {
      int idx = base + tid * 8 + i;
      run += v[i];
      if (idx < M) row_ptr[idx + 1] = run;
    }
  }
}

// ---------------------------------------------------------------------------
// K3: blocks [0,fb) chunked CSR-fill; blocks [fb,..) embedding MFMA tiles.
// ---------------------------------------------------------------------------
__global__ __launch_bounds__(256) void fill_emb(
    const int* __restrict__ rows, const int* __restrict__ cols,
    const int* __restrict__ row_ptr, int* __restrict__ fill_cnt,
    int* __restrict__ csr_col, int* __restrict__ csr_eid, int E, int fb, int NC,
    const float* __restrict__ x, const __hip_bfloat16* __restrict__ Wet,
    const float* __restrict__ b_emb, __hip_bfloat16* __restrict__ hb,
    int N, int Fn)
{
  if ((int)blockIdx.x < fb) {
    int e = blockIdx.x * 256 + threadIdx.x;
    if (e < E) {
      int c   = cols[e];
      int key = rows[e] * NC + (c >> CHUNK_SHIFT);
      int pos = atomicAdd(&fill_cnt[key], 1);
      int at  = row_ptr[key] + pos;
      csr_col[at] = c;
      csr_eid[at] = e;
    }
  } else {
    emb_tile(x, Wet, b_emb, hb, N, Fn, (blockIdx.x - fb) * 64, threadIdx.x);
  }
}

// ---------------------------------------------------------------------------
// Per-graph mean pool (bf16 h) + hidden relu + output head. One block/graph.
// ---------------------------------------------------------------------------
__global__ __launch_bounds__(128) void pool_head(
    const __hip_bfloat16* __restrict__ hb, const int* __restrict__ batch,
    const float* __restrict__ Wh, const float* __restrict__ bh,
    const float* __restrict__ Wout, const float* __restrict__ bout,
    float* __restrict__ out, int N)
{
  const int g = blockIdx.x;
  const int t = threadIdx.x;
  int lo = 0, hi = N;
  while (lo < hi) { int mid = (lo + hi) >> 1; if (batch[mid] < g) lo = mid + 1; else hi = mid; }
  int start = lo;
  hi = N;
  while (lo < hi) { int mid = (lo + hi) >> 1; if (batch[mid] < g + 1) lo = mid + 1; else hi = mid; }
  int end = lo;

  const int lane = t & 63, half = t >> 6;
  float2 a0 = {0.f, 0.f}, a1 = {0.f, 0.f}, a2 = {0.f, 0.f}, a3 = {0.f, 0.f};
  int i = start + half;
  for (; i + 6 < end; i += 8) {
    unsigned u0 = *reinterpret_cast<const unsigned*>(&hb[(size_t)(i + 0) * 128 + lane * 2]);
    unsigned u1 = *reinterpret_cast<const unsigned*>(&hb[(size_t)(i + 2) * 128 + lane * 2]);
    unsigned u2 = *reinterpret_cast<const unsigned*>(&hb[(size_t)(i + 4) * 128 + lane * 2]);
    unsigned u3 = *reinterpret_cast<const unsigned*>(&hb[(size_t)(i + 6) * 128 + lane * 2]);
    a0.x += blo(u0); a0.y += bhi(u0);
    a1.x += blo(u1); a1.y += bhi(u1);
    a2.x += blo(u2); a2.y += bhi(u2);
    a3.x += blo(u3); a3.y += bhi(u3);
  }
  for (; i < end; i += 2) {
    unsigned u = *reinterpret_cast<const unsigned*>(&hb[(size_t)i * 128 + lane * 2]);
    a0.x += blo(u); a0.y += bhi(u);
  }
  float2 sum;
  sum.x = (a0.x + a1.x) + (a2.x + a3.x);
  sum.y = (a0.y + a1.y) + (a2.y + a3.y);

  __shared__ float2 part[2][64];
  __shared__ float  gl[128];
  part[half][lane] = sum;
  __syncthreads();
  if (t < 64) {
    float inv = 1.f / fmaxf(1.f, (float)(end - start));
    float2 tot;
    tot.x = part[0][t].x + part[1][t].x;
    tot.y = part[0][t].y + part[1][t].y;
    gl[2 * t]     = tot.x * inv;
    gl[2 * t + 1] = tot.y * inv;
  }
  __syncthreads();

  float acc = bh[t];
  #pragma unroll 4
  for (int k = 0; k < 128; k++) acc += gl[k] * Wh[k * 128 + t];
  acc = fmaxf(acc, 0.f);

  __shared__ float p[128];
  p[t] = acc * Wout[t];
  __syncthreads();
  if (t < 64) {
    float v = p[t] + p[t + 64];
    #pragma unroll
    for (int o = 32; o > 0; o >>= 1) v += __shfl_down(v, o);
    if (t == 0) out[g] = v + bout[0];
  }
}

// ---------------------------------------------------------------------------
extern "C" void kernel_launch(void* const* d_in, const int* in_sizes, int n_in,
                              void* d_out, int out_size, void* d_ws, size_t ws_size,
                              hipStream_t stream)
{
  const float* x      = (const float*)d_in[0];
  const int*   eidx   = (const int*)d_in[1];
  const float* eattr  = (const float*)d_in[2];
  const int*   batch  = (const int*)d_in[3];
  const float* W_emb  = (const float*)d_in[4];
  const float* b_emb  = (const float*)d_in[5];
  const float* Wc     = (const float*)d_in[6];
  const float* bc     = (const float*)d_in[7];
  const float* gamma  = (const float*)d_in[8];
  const float* beta   = (const float*)d_in[9];
  const float* Wh     = (const float*)d_in[10];
  const float* bh     = (const float*)d_in[11];
  const float* Wout   = (const float*)d_in[12];
  const float* bout   = (const float*)d_in[13];
  float* out = (float*)d_out;

  const int N  = in_sizes[3];
  const int E  = in_sizes[1] / 2;
  const int Fn = in_sizes[0] / N;      // 92
  const int H  = in_sizes[5];          // 128
  const int L  = in_sizes[7] / H;      // 3
  const int Kc = H + in_sizes[2] / E;  // 192
  const int Kp = 96;
  const int NC = ((N - 1) >> CHUNK_SHIFT) + 1;   // col-chunks (7 for N=50000)

  const int* rows = eidx;
  const int* cols = eidx + E;

  char* ws = (char*)d_ws;
  size_t off = 0;
  auto alloc = [&](size_t bytes) { void* p = ws + off; off += (bytes + 255) / 256 * 256; return p; };
  __hip_bfloat16*  hbA      = (__hip_bfloat16*)alloc((size_t)N * 128 * 2);
  __hip_bfloat16*  hbB      = (__hip_bfloat16*)alloc((size_t)N * 128 * 2);
  __hip_bfloat16*  Tb       = (__hip_bfloat16*)alloc((size_t)N * 64 * 2);
  __hip_bfloat16*  Wet      = (__hip_bfloat16*)alloc((size_t)H * Kp * 2);
  __hip_bfloat16*  Wct      = (__hip_bfloat16*)alloc((size_t)L * H * Kc * 2);
  int*             row_ptr  = (int*)alloc(((size_t)N * NC + 1) * 4);
  int*             cnt      = (int*)alloc((size_t)N * NC * 4 * 2);
  int*             fill_cnt = cnt + (size_t)N * NC;
  int*             csr_col  = (int*)alloc((size_t)E * 4);
  int*             csr_eid  = (int*)alloc((size_t)E * 4);
  (void)ws_size; (void)n_in;

  hipMemsetAsync(cnt, 0, (size_t)N * NC * 8, stream);

  // K1: weight convert || chunked histogram
  const int wtot = H * Kp + L * H * Kc;
  const int wb   = (wtot + 255) / 256;
  const int hbk  = (E + 255) / 256;
  prep_hist<<<dim3(wb + hbk), 256, 0, stream>>>(
      W_emb, Wet, Wc, Wct, rows, cols, cnt, E, wb, Fn, Kp, H, L, Kc, NC);

  scan_kernel<<<dim3(1), 1024, 0, stream>>>(cnt, row_ptr, N * NC);

  // K3: CSR fill || embedding GEMM
  const int fb  = (E + 255) / 256;
  const int eb  = (N + 63) / 64;
  fill_emb<<<dim3(fb + eb), 256, 0, stream>>>(
      rows, cols, row_ptr, fill_cnt, csr_col, csr_eid, E, fb, NC,
      x, Wet, b_emb, hbA, N, Fn);

  // conv layers (layer 0 computes T inline from eattr and stores Tb)
  conv_fused<true><<<dim3((N + 63) / 64), 256, 0, stream>>>(
      hbA, row_ptr, csr_col, csr_eid, eattr, Tb, Wct,
      bc, gamma, beta, hbB, N, NC);
  conv_fused<false><<<dim3((N + 63) / 64), 256, 0, stream>>>(
      hbB, row_ptr, csr_col, csr_eid, eattr, Tb, Wct + (size_t)H * Kc,
      bc + H, gamma + H, beta + H, hbA, N, NC);
  conv_fused<false><<<dim3((N + 63) / 64), 256, 0, stream>>>(
      hbA, row_ptr, csr_col, csr_eid, eattr, Tb, Wct + (size_t)2 * H * Kc,
      bc + 2 * H, gamma + 2 * H, beta + 2 * H, hbB, N, NC);

  pool_head<<<dim3(out_size), 128, 0, stream>>>(hbB, batch, Wh, bh, Wout, bout, out, N);
}

// Round 9
// 346.924 us; speedup vs baseline: 2.6502x; 2.6502x over previous
//
#include <hip/hip_runtime.h>
#include <hip/hip_bf16.h>
#include <cstdint>
#include <cstddef>

#define BN_EPS 1e-3f

typedef __attribute__((ext_vector_type(8))) short bf16x8;
typedef __attribute__((ext_vector_type(4))) float f32x4;

__device__ __forceinline__ float blo(unsigned u) {
  union { unsigned i; float f; } v; v.i = u << 16; return v.f;
}
__device__ __forceinline__ float bhi(unsigned u) {
  union { unsigned i; float f; } v; v.i = u & 0xffff0000u; return v.f;
}
__device__ __forceinline__ unsigned pk2(float a, float b) {
  __hip_bfloat162 t = __float22bfloat162_rn(make_float2(a, b));
  return *reinterpret_cast<unsigned*>(&t);
}
__device__ __forceinline__ void acc_pk(float* acc, uint4 u) {
  acc[0] += blo(u.x); acc[1] += bhi(u.x);
  acc[2] += blo(u.y); acc[3] += bhi(u.y);
  acc[4] += blo(u.z); acc[5] += bhi(u.z);
  acc[6] += blo(u.w); acc[7] += bhi(u.w);
}

// ---------------------------------------------------------------------------
// Embedding MFMA tile body (shared by fill_emb). Reads x fp32, cvt in-reg.
// hb = bf16(relu(x @ Wet^T + bias)). 64x128 tile, 4 waves 2x2.
// ---------------------------------------------------------------------------
__device__ __forceinline__ void emb_tile(
    const float* __restrict__ x,
    const __hip_bfloat16* __restrict__ Bt,   // [128][96]
    const float* __restrict__ bias,
    __hip_bfloat16* __restrict__ hb, int N, int Fn, int m0, int tid)
{
  constexpr int KP = 96;
  const int w    = tid >> 6, lane = tid & 63;
  const int wr   = w >> 1,   wc   = w & 1;
  const int lr   = lane & 15;
  const int kg   = lane >> 4;

  f32x4 acc[2][4] = {};
  const int rowA0 = m0 + wr * 32 + lr;

  #pragma unroll
  for (int ks = 0; ks < KP / 32; ks++) {
    const int k0 = ks * 32 + kg * 8;
    bf16x8 a[2], b[4];
    #pragma unroll
    for (int m = 0; m < 2; m++) {
      int r = rowA0 + m * 16;
      r = (r < N) ? r : 0;
      const float* px = &x[(size_t)r * Fn + k0];
      float4 v0 = make_float4(0.f, 0.f, 0.f, 0.f);
      float4 v1 = make_float4(0.f, 0.f, 0.f, 0.f);
      if (k0 + 8 <= Fn) {
        v0 = *reinterpret_cast<const float4*>(px);
        v1 = *reinterpret_cast<const float4*>(px + 4);
      } else if (k0 + 4 <= Fn) {
        v0 = *reinterpret_cast<const float4*>(px);
        if (k0 + 5 <= Fn) v1.x = px[4];
        if (k0 + 6 <= Fn) v1.y = px[5];
        if (k0 + 7 <= Fn) v1.z = px[6];
      } else if (k0 < Fn) {
        if (k0 + 1 <= Fn) v0.x = px[0];
        if (k0 + 2 <= Fn) v0.y = px[1];
        if (k0 + 3 <= Fn) v0.z = px[2];
      }
      uint4 pu;
      pu.x = pk2(v0.x, v0.y); pu.y = pk2(v0.z, v0.w);
      pu.z = pk2(v1.x, v1.y); pu.w = pk2(v1.z, v1.w);
      a[m] = *reinterpret_cast<bf16x8*>(&pu);
    }
    #pragma unroll
    for (int n = 0; n < 4; n++) {
      int c = wc * 64 + n * 16 + lr;
      b[n] = *reinterpret_cast<const bf16x8*>(&Bt[(size_t)c * KP + k0]);
    }
    #pragma unroll
    for (int m = 0; m < 2; m++)
      #pragma unroll
      for (int n = 0; n < 4; n++)
        acc[m][n] = __builtin_amdgcn_mfma_f32_16x16x32_bf16(a[m], b[n], acc[m][n], 0, 0, 0);
  }

  #pragma unroll
  for (int n = 0; n < 4; n++) {
    const int c = wc * 64 + n * 16 + lr;
    const float bb = bias[c];
    #pragma unroll
    for (int m = 0; m < 2; m++) {
      #pragma unroll
      for (int j = 0; j < 4; j++) {
        int grow = m0 + wr * 32 + m * 16 + kg * 4 + j;
        if (grow < N) {
          float v = fmaxf(acc[m][n][j] + bb, 0.f);
          hb[(size_t)grow * 128 + c] = __float2bfloat16(v);
        }
      }
    }
  }
}

// ---------------------------------------------------------------------------
// Fused conv layer, bf16 residual chain, 32-row tiles, 16-deep gather MLP:
//   hbo = bf16( hbi + relu( (gather(hbi) ++ T) @ Wct / deg * bn_scale + ofs ) )
// 16 groups x 16 lanes; group g owns rows {g, g+16}. hbi/hbo ping-pong.
// ---------------------------------------------------------------------------
__global__ __launch_bounds__(256) void conv_fused(
    const __hip_bfloat16* __restrict__ hbi,
    const int* __restrict__ row_ptr,
    const int* __restrict__ csr_col,
    const __hip_bfloat16* __restrict__ Tb,    // [N][64]
    const __hip_bfloat16* __restrict__ Wct,   // [128][192]
    const float* __restrict__ bc,
    const float* __restrict__ gamma,
    const float* __restrict__ beta,
    __hip_bfloat16* __restrict__ hbo, int N)
{
  constexpr int K   = 192;
  constexpr int LDK = 200;
  __shared__ __hip_bfloat16 As[32 * LDK];   // 12.8 KB
  __shared__ float sinv[32];

  const int tid = threadIdx.x;
  const int m0  = blockIdx.x * 32;

  // ---- gather phase
  {
    const int g   = tid >> 4;
    const int gl  = tid & 15;
    const int gb  = (tid & 63) & ~15;    // group base lane within wave (for shfl)

    #pragma unroll
    for (int rr = 0; rr < 2; rr++) {
      const int r  = g + rr * 16;
      const int gr = m0 + r;
      float acc[8] = {};
      int len = 0;
      if (gr < N) {
        const int s = row_ptr[gr];
        len = row_ptr[gr + 1] - s;
        for (int b = 0; b < len; b += 16) {
          const int m  = min(16, len - b);
          const int cv = (gl < m) ? csr_col[s + b + gl] : 0;
          int j = 0;
          for (; j + 16 <= m; j += 16) {
            uint4 u[16];
            #pragma unroll
            for (int t = 0; t < 16; t++) {
              int c = __shfl(cv, gb + j + t);
              u[t] = *reinterpret_cast<const uint4*>(&hbi[(size_t)c * 128 + gl * 8]);
            }
            #pragma unroll
            for (int t = 0; t < 16; t++) acc_pk(acc, u[t]);
          }
          for (; j + 8 <= m; j += 8) {
            uint4 u[8];
            #pragma unroll
            for (int t = 0; t < 8; t++) {
              int c = __shfl(cv, gb + j + t);
              u[t] = *reinterpret_cast<const uint4*>(&hbi[(size_t)c * 128 + gl * 8]);
            }
            #pragma unroll
            for (int t = 0; t < 8; t++) acc_pk(acc, u[t]);
          }
          for (; j + 4 <= m; j += 4) {
            uint4 u[4];
            #pragma unroll
            for (int t = 0; t < 4; t++) {
              int c = __shfl(cv, gb + j + t);
              u[t] = *reinterpret_cast<const uint4*>(&hbi[(size_t)c * 128 + gl * 8]);
            }
            #pragma unroll
            for (int t = 0; t < 4; t++) acc_pk(acc, u[t]);
          }
          for (; j < m; ++j) {
            int c = __shfl(cv, gb + j);
            uint4 u = *reinterpret_cast<const uint4*>(&hbi[(size_t)c * 128 + gl * 8]);
            acc_pk(acc, u);
          }
        }
      }
      uint4 o;
      o.x = pk2(acc[0], acc[1]); o.y = pk2(acc[2], acc[3]);
      o.z = pk2(acc[4], acc[5]); o.w = pk2(acc[6], acc[7]);
      *reinterpret_cast<uint4*>(&As[r * LDK + gl * 8]) = o;
      if (gl == 0) sinv[r] = 1.f / fmaxf(1.f, (float)len);
    }
  }
  // ---- T-tile copy: 32 rows x 64 cols bf16 = 256 x 16B chunks
  {
    int r   = tid >> 3;
    int ko  = (tid & 7) * 8;
    int gr  = m0 + r;
    uint4 v = make_uint4(0, 0, 0, 0);
    if (gr < N) v = *reinterpret_cast<const uint4*>(&Tb[(size_t)gr * 64 + ko]);
    *reinterpret_cast<uint4*>(&As[r * LDK + 128 + ko]) = v;
  }
  __syncthreads();

  // ---- MFMA phase: 4 waves, wave w owns cols [w*32, w*32+32)
  const int w    = tid >> 6, lane = tid & 63;
  const int lr   = lane & 15;
  const int kg   = lane >> 4;

  f32x4 acc[2][2] = {};
  #pragma unroll
  for (int ks = 0; ks < K / 32; ks++) {
    const int k0 = ks * 32 + kg * 8;
    bf16x8 a[2], b[2];
    #pragma unroll
    for (int m = 0; m < 2; m++)
      a[m] = *reinterpret_cast<const bf16x8*>(&As[(lr + m * 16) * LDK + k0]);
    #pragma unroll
    for (int n = 0; n < 2; n++) {
      int c = w * 32 + n * 16 + lr;
      b[n] = *reinterpret_cast<const bf16x8*>(&Wct[(size_t)c * K + k0]);
    }
    #pragma unroll
    for (int m = 0; m < 2; m++)
      #pragma unroll
      for (int n = 0; n < 2; n++)
        acc[m][n] = __builtin_amdgcn_mfma_f32_16x16x32_bf16(a[m], b[n], acc[m][n], 0, 0, 0);
  }

  const float rs = rsqrtf(1.f + BN_EPS);
  #pragma unroll
  for (int n = 0; n < 2; n++) {
    const int c   = w * 32 + n * 16 + lr;
    const float sc  = gamma[c] * rs;
    const float ofs = bc[c] * sc + beta[c];
    #pragma unroll
    for (int m = 0; m < 2; m++) {
      #pragma unroll
      for (int j = 0; j < 4; j++) {
        int lrow = m * 16 + kg * 4 + j;
        int grow = m0 + lrow;
        if (grow < N) {
          float v    = acc[m][n][j] * sc * sinv[lrow] + ofs;
          float hold = __bfloat162float(hbi[(size_t)grow * 128 + c]);
          float hn   = hold + fmaxf(v, 0.f);
          hbo[(size_t)grow * 128 + c] = __float2bfloat16(hn);
        }
      }
    }
  }
}

// ---------------------------------------------------------------------------
// K1: blocks [0,wb) convert weights; blocks [wb,..) histogram row degrees
// (cnt pre-zeroed by memsetAsync).
// ---------------------------------------------------------------------------
__global__ void prep_hist(
    const float* __restrict__ W_emb, __hip_bfloat16* __restrict__ Wet,
    const float* __restrict__ Wc, __hip_bfloat16* __restrict__ Wct,
    const int* __restrict__ rows, int* __restrict__ cnt,
    int E, int wb, int Fn, int Kp, int H, int L, int Kc)
{
  if ((int)blockIdx.x < wb) {
    int i = blockIdx.x * 256 + threadIdx.x;
    if (i < H * Kp) {
      int c = i / Kp, k = i - c * Kp;
      Wet[i] = __float2bfloat16(k < Fn ? W_emb[(size_t)k * H + c] : 0.f);
    } else if (i < H * Kp + L * H * Kc) {
      int j = i - H * Kp;
      int l   = j / (H * Kc);
      int rem = j - l * (H * Kc);
      int c   = rem / Kc;
      int k   = rem - c * Kc;
      Wct[j] = __float2bfloat16(Wc[(size_t)l * Kc * H + (size_t)k * H + c]);
    }
  } else {
    int e = (blockIdx.x - wb) * 256 + threadIdx.x;
    if (e < E) atomicAdd(&cnt[rows[e]], 1);
  }
}

// ---------------------------------------------------------------------------
// Multi-block scan, phase 1: per-block (2048 elems) local inclusive scan into
// row_ptr[idx+1]; block total into part[b].
// ---------------------------------------------------------------------------
__global__ __launch_bounds__(256) void scan_part(
    const int* __restrict__ cnt, int* __restrict__ row_ptr,
    int* __restrict__ part, int M)
{
  __shared__ int wsum[4];
  const int tid  = threadIdx.x;
  const int lane = tid & 63, wid = tid >> 6;
  const int base = blockIdx.x * 2048;

  int v[8]; int s = 0;
  #pragma unroll
  for (int i = 0; i < 8; i++) {
    int idx = base + tid * 8 + i;
    v[i] = (idx < M) ? cnt[idx] : 0;
    s += v[i];
  }
  int sc = s;
  #pragma unroll
  for (int o = 1; o < 64; o <<= 1) {
    int u = __shfl_up(sc, o);
    if (lane >= o) sc += u;
  }
  if (lane == 63) wsum[wid] = sc;
  __syncthreads();
  int woff = 0;
  #pragma unroll
  for (int i = 0; i < 4; i++) if (i < wid) woff += wsum[i];
  int run = woff + (sc - s);
  #pragma unroll
  for (int i = 0; i < 8; i++) {
    int idx = base + tid * 8 + i;
    run += v[i];
    if (idx < M) row_ptr[idx + 1] = run;
  }
  if (tid == 0) part[blockIdx.x] = wsum[0] + wsum[1] + wsum[2] + wsum[3];
}

// ---------------------------------------------------------------------------
// Multi-block scan, phase 2: add exclusive-prefix of part[] to each segment.
// ---------------------------------------------------------------------------
__global__ __launch_bounds__(256) void scan_add(
    int* __restrict__ row_ptr, const int* __restrict__ part, int M, int SB)
{
  __shared__ int soff;
  const int b   = blockIdx.x;
  const int tid = threadIdx.x;
  if (tid < 64) {
    int x = (tid < b) ? part[tid] : 0;   // SB <= 64 assumed
    #pragma unroll
    for (int o = 32; o > 0; o >>= 1) x += __shfl_down(x, o);
    if (tid == 0) { soff = x; if (b == 0) row_ptr[0] = 0; }
  }
  __syncthreads();
  const int off  = soff;
  const int base = b * 2048;
  if (off != 0) {
    #pragma unroll
    for (int i = 0; i < 8; i++) {
      int idx = base + i * 256 + tid;
      if (idx < M) row_ptr[idx + 1] += off;
    }
  }
}

// ---------------------------------------------------------------------------
// K3: blocks [0,fb) CSR-fill; blocks [fb,..) embedding MFMA tiles.
// ---------------------------------------------------------------------------
__global__ __launch_bounds__(256) void fill_emb(
    const int* __restrict__ rows, const int* __restrict__ cols,
    const int* __restrict__ row_ptr, int* __restrict__ fill_cnt,
    int* __restrict__ csr_col, int* __restrict__ csr_eid, int E, int fb,
    const float* __restrict__ x, const __hip_bfloat16* __restrict__ Wet,
    const float* __restrict__ b_emb, __hip_bfloat16* __restrict__ hb,
    int N, int Fn)
{
  if ((int)blockIdx.x < fb) {
    int e = blockIdx.x * 256 + threadIdx.x;
    if (e < E) {
      int r   = rows[e];
      int pos = atomicAdd(&fill_cnt[r], 1);
      int at  = row_ptr[r] + pos;
      csr_col[at] = cols[e];
      csr_eid[at] = e;
    }
  } else {
    emb_tile(x, Wet, b_emb, hb, N, Fn, (blockIdx.x - fb) * 64, threadIdx.x);
  }
}

// ---------------------------------------------------------------------------
// Tb = segment_sum(edge_attr) [N][64] bf16. One wave per row, 8-deep MLP.
// ---------------------------------------------------------------------------
__global__ __launch_bounds__(256) void build_T(
    const float* __restrict__ eattr, const int* __restrict__ row_ptr,
    const int* __restrict__ csr_eid, __hip_bfloat16* __restrict__ Tb, int N)
{
  int r = blockIdx.x * 4 + (threadIdx.x >> 6);
  if (r >= N) return;
  int lane = threadIdx.x & 63;
  int s = row_ptr[r], len = row_ptr[r + 1] - s;
  float acc = 0.f;
  for (int b = 0; b < len; b += 64) {
    int m  = min(64, len - b);
    int ev = (lane < m) ? csr_eid[s + b + lane] : 0;
    int j  = 0;
    for (; j + 8 <= m; j += 8) {
      float a[8];
      #pragma unroll
      for (int t = 0; t < 8; t++) {
        int e0 = __shfl(ev, j + t);
        a[t] = eattr[(size_t)e0 * 64 + lane];
      }
      acc += (a[0] + a[1]) + (a[2] + a[3]);
      acc += (a[4] + a[5]) + (a[6] + a[7]);
    }
    for (; j + 4 <= m; j += 4) {
      float a[4];
      #pragma unroll
      for (int t = 0; t < 4; t++) {
        int e0 = __shfl(ev, j + t);
        a[t] = eattr[(size_t)e0 * 64 + lane];
      }
      acc += (a[0] + a[1]) + (a[2] + a[3]);
    }
    for (; j < m; ++j) {
      int e0 = __shfl(ev, j);
      acc += eattr[(size_t)e0 * 64 + lane];
    }
  }
  Tb[(size_t)r * 64 + lane] = __float2bfloat16(acc);
}

// ---------------------------------------------------------------------------
// Per-graph mean pool (bf16 h) + hidden relu + output head. One block/graph.
// ---------------------------------------------------------------------------
__global__ __launch_bounds__(128) void pool_head(
    const __hip_bfloat16* __restrict__ hb, const int* __restrict__ batch,
    const float* __restrict__ Wh, const float* __restrict__ bh,
    const float* __restrict__ Wout, const float* __restrict__ bout,
    float* __restrict__ out, int N)
{
  const int g = blockIdx.x;
  const int t = threadIdx.x;
  int lo = 0, hi = N;
  while (lo < hi) { int mid = (lo + hi) >> 1; if (batch[mid] < g) lo = mid + 1; else hi = mid; }
  int start = lo;
  hi = N;
  while (lo < hi) { int mid = (lo + hi) >> 1; if (batch[mid] < g + 1) lo = mid + 1; else hi = mid; }
  int end = lo;

  const int lane = t & 63, half = t >> 6;
  float2 a0 = {0.f, 0.f}, a1 = {0.f, 0.f}, a2 = {0.f, 0.f}, a3 = {0.f, 0.f};
  int i = start + half;
  for (; i + 6 < end; i += 8) {
    unsigned u0 = *reinterpret_cast<const unsigned*>(&hb[(size_t)(i + 0) * 128 + lane * 2]);
    unsigned u1 = *reinterpret_cast<const unsigned*>(&hb[(size_t)(i + 2) * 128 + lane * 2]);
    unsigned u2 = *reinterpret_cast<const unsigned*>(&hb[(size_t)(i + 4) * 128 + lane * 2]);
    unsigned u3 = *reinterpret_cast<const unsigned*>(&hb[(size_t)(i + 6) * 128 + lane * 2]);
    a0.x += blo(u0); a0.y += bhi(u0);
    a1.x += blo(u1); a1.y += bhi(u1);
    a2.x += blo(u2); a2.y += bhi(u2);
    a3.x += blo(u3); a3.y += bhi(u3);
  }
  for (; i < end; i += 2) {
    unsigned u = *reinterpret_cast<const unsigned*>(&hb[(size_t)i * 128 + lane * 2]);
    a0.x += blo(u); a0.y += bhi(u);
  }
  float2 sum;
  sum.x = (a0.x + a1.x) + (a2.x + a3.x);
  sum.y = (a0.y + a1.y) + (a2.y + a3.y);

  __shared__ float2 part[2][64];
  __shared__ float  gl[128];
  part[half][lane] = sum;
  __syncthreads();
  if (t < 64) {
    float inv = 1.f / fmaxf(1.f, (float)(end - start));
    float2 tot;
    tot.x = part[0][t].x + part[1][t].x;
    tot.y = part[0][t].y + part[1][t].y;
    gl[2 * t]     = tot.x * inv;
    gl[2 * t + 1] = tot.y * inv;
  }
  __syncthreads();

  float acc = bh[t];
  #pragma unroll 4
  for (int k = 0; k < 128; k++) acc += gl[k] * Wh[k * 128 + t];
  acc = fmaxf(acc, 0.f);

  __shared__ float p[128];
  p[t] = acc * Wout[t];
  __syncthreads();
  if (t < 64) {
    float v = p[t] + p[t + 64];
    #pragma unroll
    for (int o = 32; o > 0; o >>= 1) v += __shfl_down(v, o);
    if (t == 0) out[g] = v + bout[0];
  }
}

// ---------------------------------------------------------------------------
extern "C" void kernel_launch(void* const* d_in, const int* in_sizes, int n_in,
                              void* d_out, int out_size, void* d_ws, size_t ws_size,
                              hipStream_t stream)
{
  const float* x      = (const float*)d_in[0];
  const int*   eidx   = (const int*)d_in[1];
  const float* eattr  = (const float*)d_in[2];
  const int*   batch  = (const int*)d_in[3];
  const float* W_emb  = (const float*)d_in[4];
  const float* b_emb  = (const float*)d_in[5];
  const float* Wc     = (const float*)d_in[6];
  const float* bc     = (const float*)d_in[7];
  const float* gamma  = (const float*)d_in[8];
  const float* beta   = (const float*)d_in[9];
  const float* Wh     = (const float*)d_in[10];
  const float* bh     = (const float*)d_in[11];
  const float* Wout   = (const float*)d_in[12];
  const float* bout   = (const float*)d_in[13];
  float* out = (float*)d_out;

  const int N  = in_sizes[3];
  const int E  = in_sizes[1] / 2;
  const int Fn = in_sizes[0] / N;      // 92
  const int H  = in_sizes[5];          // 128
  const int L  = in_sizes[7] / H;      // 3
  const int Kc = H + in_sizes[2] / E;  // 192
  const int Kp = 96;

  const int* rows = eidx;
  const int* cols = eidx + E;

  char* ws = (char*)d_ws;
  size_t off = 0;
  auto alloc = [&](size_t bytes) { void* p = ws + off; off += (bytes + 255) / 256 * 256; return p; };
  __hip_bfloat16*  hbA      = (__hip_bfloat16*)alloc((size_t)N * 128 * 2);
  __hip_bfloat16*  hbB      = (__hip_bfloat16*)alloc((size_t)N * 128 * 2);
  __hip_bfloat16*  Tb       = (__hip_bfloat16*)alloc((size_t)N * 64 * 2);
  __hip_bfloat16*  Wet      = (__hip_bfloat16*)alloc((size_t)H * Kp * 2);
  __hip_bfloat16*  Wct      = (__hip_bfloat16*)alloc((size_t)L * H * Kc * 2);
  int*             row_ptr  = (int*)alloc((size_t)(N + 1) * 4);
  int*             cnt      = (int*)alloc((size_t)N * 4 * 2);
  int*             fill_cnt = cnt + N;
  int*             part     = (int*)alloc(64 * 4);
  int*             csr_col  = (int*)alloc((size_t)E * 4);
  int*             csr_eid  = (int*)alloc((size_t)E * 4);
  (void)ws_size; (void)n_in;

  hipMemsetAsync(cnt, 0, (size_t)N * 8, stream);

  // K1: weight convert || histogram
  const int wtot = H * Kp + L * H * Kc;
  const int wb   = (wtot + 255) / 256;
  const int hbk  = (E + 255) / 256;
  prep_hist<<<dim3(wb + hbk), 256, 0, stream>>>(
      W_emb, Wet, Wc, Wct, rows, cnt, E, wb, Fn, Kp, H, L, Kc);

  // two-phase parallel scan (SB <= 64 for N <= 131072)
  const int SB = (N + 2047) / 2048;
  scan_part<<<dim3(SB), 256, 0, stream>>>(cnt, row_ptr, part, N);
  scan_add<<<dim3(SB), 256, 0, stream>>>(row_ptr, part, N, SB);

  // K3: CSR fill || embedding GEMM
  const int fb  = (E + 255) / 256;
  const int eb  = (N + 63) / 64;
  fill_emb<<<dim3(fb + eb), 256, 0, stream>>>(
      rows, cols, row_ptr, fill_cnt, csr_col, csr_eid, E, fb,
      x, Wet, b_emb, hbA, N, Fn);

  // T (layer-invariant, bf16)
  build_T<<<dim3((N + 3) / 4), 256, 0, stream>>>(eattr, row_ptr, csr_eid, Tb, N);

  // conv layers (32-row tiles)
  __hip_bfloat16* hb_in  = hbA;
  __hip_bfloat16* hb_out = hbB;
  for (int l = 0; l < L; l++) {
    conv_fused<<<dim3((N + 31) / 32), 256, 0, stream>>>(
        hb_in, row_ptr, csr_col, Tb, Wct + (size_t)l * H * Kc,
        bc + (size_t)l * H, gamma + (size_t)l * H, beta + (size_t)l * H, hb_out, N);
    __hip_bfloat16* tmp = hb_in; hb_in = hb_out; hb_out = tmp;
  }

  pool_head<<<dim3(out_size), 128, 0, stream>>>(hb_in, batch, Wh, bh, Wout, bout, out, N);
}